// Round 8
// baseline (94.588 us; speedup 1.0000x reference)
//
#include <hip/hip_runtime.h>

#define HH 2160
#define WW 3840
#define K 31
#define RAD 15
#define TW 64
#define TH 32
#define IW 96             // staged cols: gx in [x0-16, x0+80)
#define IH 62             // TH + K - 1
#define NTHREADS 256
#define NF4 (IH * (IW / 4))   // 1488 float4 staged
#define TMPW 100          // padded s_tmp row stride
#define NTY 68            // ceil(2160/32): last tile row partial

typedef float v2f __attribute__((ext_vector_type(2)));

#define GLDS(gp, lp) __builtin_amdgcn_global_load_lds(                         \
    (const __attribute__((address_space(1))) void*)(gp),                       \
    (__attribute__((address_space(3))) void*)(lp), 16, 0, 0)

__device__ __forceinline__ float fcomp(float4 v, int p) {
    switch (p) { case 0: return v.x; case 1: return v.y; case 2: return v.z; default: return v.w; }
}

__device__ __forceinline__ float uniformf(float x) {
    return __uint_as_float(__builtin_amdgcn_readfirstlane(__float_as_uint(x)));
}

__global__ __launch_bounds__(NTHREADS, 4) void blur_masked_kernel(
    const float* __restrict__ img, const float* __restrict__ mask,
    const float* __restrict__ kern, float* __restrict__ out)
{
    __shared__ float s_in[NF4 * 4];        // 62x96 = 23.25 KB
    __shared__ float s_tmp[TH * TMPW];     // 12.5 KB
    __shared__ float s_k1[K];

    const int b  = blockIdx.x;
    const int tx = b % 60;
    const int ty = b / 60;
    const int x0 = tx * TW;
    const int y0 = ty * TH;
    const int t  = threadIdx.x;

    // thread -> output pixels: rows (hr, hr+16), cols hc0..hc0+3
    const int hr  = t >> 4;         // 0..15
    const int hc0 = (t & 15) * 4;   // 0,4,...,60
    const int gyA = y0 + hr;               // always < 2160
    const int gyB = y0 + hr + 16;
    const bool validB = (gyB < HH);

    // ---- 1D kernel = row sums of 2D kernel (identical per channel) ----
    if (t < K) {
        float s = 0.f;
        const float* kr = kern + t * K;
        #pragma unroll
        for (int j = 0; j < K; ++j) s += kr[j];
        s_k1[t] = s;
    }

    // ---- mask + img prefetch for both row-quads ----
    const size_t HW = (size_t)HH * WW;
    const size_t pixA = (size_t)gyA * WW + (x0 + hc0);
    const size_t pixB = (size_t)gyB * WW + (x0 + hc0);
    float4 mvA = *(const float4*)(mask + pixA);
    float4 mvB = make_float4(0.f, 0.f, 0.f, 0.f);
    if (validB) mvB = *(const float4*)(mask + pixB);

    int anyLocal = (mvA.x != 0.f) | (mvA.y != 0.f) | (mvA.z != 0.f) | (mvA.w != 0.f) |
                   (mvB.x != 0.f) | (mvB.y != 0.f) | (mvB.z != 0.f) | (mvB.w != 0.f);
    int any = __syncthreads_or(anyLocal);   // also publishes s_k1

    if (!any) {
        // pure copy: out = img * 255
        float4 a0 = *(const float4*)(img + pixA);
        float4 a1 = *(const float4*)(img + HW + pixA);
        float4 a2 = *(const float4*)(img + 2 * HW + pixA);
        float* obA = out + pixA * 3;
        *(float4*)(obA)     = make_float4(a0.x * 255.f, a1.x * 255.f, a2.x * 255.f, a0.y * 255.f);
        *(float4*)(obA + 4) = make_float4(a1.y * 255.f, a2.y * 255.f, a0.z * 255.f, a1.z * 255.f);
        *(float4*)(obA + 8) = make_float4(a2.z * 255.f, a0.w * 255.f, a1.w * 255.f, a2.w * 255.f);
        if (validB) {
            float4 b0 = *(const float4*)(img + pixB);
            float4 b1 = *(const float4*)(img + HW + pixB);
            float4 b2 = *(const float4*)(img + 2 * HW + pixB);
            float* obB = out + pixB * 3;
            *(float4*)(obB)     = make_float4(b0.x * 255.f, b1.x * 255.f, b2.x * 255.f, b0.y * 255.f);
            *(float4*)(obB + 4) = make_float4(b1.y * 255.f, b2.y * 255.f, b0.z * 255.f, b1.z * 255.f);
            *(float4*)(obB + 8) = make_float4(b2.z * 255.f, b0.w * 255.f, b1.w * 255.f, b2.w * 255.f);
        }
        return;
    }

    // taps -> SGPRs (wave-uniform)
    float k1r[K];
    #pragma unroll
    for (int j = 0; j < K; ++j) k1r[j] = uniformf(s_k1[j]);

    // interior tile: whole halo in-bounds (staged gy in [y0-15, y0+46])
    const bool interior = (tx >= 1) && (tx <= 58) && (ty >= 1) && (ty <= 66);

    auto stage = [&](int ch) {
        const float* imc = img + (size_t)ch * HW;
        if (interior) {
            #pragma unroll
            for (int k2 = 0; k2 < 6; ++k2) {
                int i = t + k2 * NTHREADS;            // 0..1535, active < 1488
                if (i < NF4) {
                    int r = i / (IW / 4), c4 = i % (IW / 4);
                    const float* gp = imc + (size_t)(y0 - RAD + r) * WW + (x0 - 16 + 4 * c4);
                    GLDS(gp, s_in + 4 * i);
                }
            }
        } else {
            #pragma unroll
            for (int k2 = 0; k2 < 6; ++k2) {
                int i = t + k2 * NTHREADS;
                if (i < NF4) {
                    int r = i / (IW / 4), c4 = i % (IW / 4);
                    int gy = y0 - RAD + r, gx = x0 - 16 + 4 * c4;
                    float4 v = make_float4(0.f, 0.f, 0.f, 0.f);
                    if (gy >= 0 && gy < HH && gx >= 0 && gx < WW)
                        v = *(const float4*)(imc + (size_t)gy * WW + gx);
                    *(float4*)(s_in + 4 * i) = v;
                }
            }
        }
    };

    stage(0);

    float oA[12], oB[12];   // final interleaved pixels, built per channel

    // V-pass mapping: 192 active threads = (column-pair, 8-row quarter)
    const int cp = t % 48;       // cols 2cp, 2cp+1
    const int vh = t / 48;       // 0..3 active; t >= 192 idle

    #pragma unroll
    for (int ch = 0; ch < 3; ++ch) {
        __syncthreads();   // staging(ch) done; prev H-pass s_tmp reads done

        // ---- vertical pass: stream 38 rows, 8 float2 running accumulators ----
        if (vh < 4) {
            v2f acc[8];
            #pragma unroll
            for (int a = 0; a < 8; ++a) acc[a] = 0.f;
            const int ybase = vh * 8;
            #pragma unroll
            for (int s = 0; s < 38; ++s) {
                v2f v = *(const v2f*)&s_in[(ybase + s) * IW + 2 * cp];
                #pragma unroll
                for (int a = 0; a < 8; ++a) {
                    if (s - a >= 0 && s - a <= 30) acc[a] += v * k1r[s - a];
                }
            }
            #pragma unroll
            for (int a = 0; a < 8; ++a)
                *(v2f*)&s_tmp[(ybase + a) * TMPW + 2 * cp] = acc[a];
        }
        // capture img values for blend while s_in holds this channel
        float4 ivA = *(const float4*)(s_in + (hr + RAD) * IW + hc0 + 16);
        float4 ivB = *(const float4*)(s_in + (hr + 16 + RAD) * IW + hc0 + 16);

        __syncthreads();   // s_tmp ready; s_in free

        if (ch < 2) stage(ch + 1);   // HBM latency hides under H-pass

        // ---- horizontal pass: sliding window, rows hr and hr+16 ----
        float aA0 = 0.f, aA1 = 0.f, aA2 = 0.f, aA3 = 0.f;
        float aB0 = 0.f, aB1 = 0.f, aB2 = 0.f, aB3 = 0.f;
        const float* rowA = s_tmp + hr * TMPW + hc0;
        const float* rowB = s_tmp + (hr + 16) * TMPW + hc0;
        #pragma unroll
        for (int q = 0; q < 9; ++q) {
            float4 wA = *(const float4*)(rowA + 4 * q);
            float4 wB = *(const float4*)(rowB + 4 * q);
            #pragma unroll
            for (int e = 0; e < 4; ++e) {
                const int idx = 4 * q + e;   // window col offset 0..35
                float vA = fcomp(wA, e);
                float vB = fcomp(wB, e);
                if (idx - 1 >= 0 && idx - 1 <= 30) { aA0 += vA * k1r[idx - 1]; aB0 += vB * k1r[idx - 1]; }
                if (idx - 2 >= 0 && idx - 2 <= 30) { aA1 += vA * k1r[idx - 2]; aB1 += vB * k1r[idx - 2]; }
                if (idx - 3 >= 0 && idx - 3 <= 30) { aA2 += vA * k1r[idx - 3]; aB2 += vB * k1r[idx - 3]; }
                if (idx - 4 >= 0 && idx - 4 <= 30) { aA3 += vA * k1r[idx - 4]; aB3 += vB * k1r[idx - 4]; }
            }
        }

        // ---- blend this channel into interleaved output registers ----
        float blA[4] = {aA0, aA1, aA2, aA3};
        float blB[4] = {aB0, aB1, aB2, aB3};
        #pragma unroll
        for (int p = 0; p < 4; ++p) {
            float mA = fcomp(mvA, p);
            float mB = fcomp(mvB, p);
            oA[p * 3 + ch] = (fcomp(ivA, p) * (1.f - mA) + blA[p] * mA) * 255.f;
            oB[p * 3 + ch] = (fcomp(ivB, p) * (1.f - mB) + blB[p] * mB) * 255.f;
        }
    }

    // ---- aligned float4 stores (full-line coalesced) ----
    float* obA = out + pixA * 3;
    *(float4*)(obA)     = make_float4(oA[0], oA[1], oA[2],  oA[3]);
    *(float4*)(obA + 4) = make_float4(oA[4], oA[5], oA[6],  oA[7]);
    *(float4*)(obA + 8) = make_float4(oA[8], oA[9], oA[10], oA[11]);
    if (validB) {
        float* obB = out + pixB * 3;
        *(float4*)(obB)     = make_float4(oB[0], oB[1], oB[2],  oB[3]);
        *(float4*)(obB + 4) = make_float4(oB[4], oB[5], oB[6],  oB[7]);
        *(float4*)(obB + 8) = make_float4(oB[8], oB[9], oB[10], oB[11]);
    }
}

extern "C" void kernel_launch(void* const* d_in, const int* in_sizes, int n_in,
                              void* d_out, int out_size, void* d_ws, size_t ws_size,
                              hipStream_t stream) {
    const float* img  = (const float*)d_in[0];
    const float* mask = (const float*)d_in[1];
    const float* kern = (const float*)d_in[2];
    float* out = (float*)d_out;
    int nblocks = 60 * NTY;  // 60 x 68 = 4080
    blur_masked_kernel<<<nblocks, NTHREADS, 0, stream>>>(img, mask, kern, out);
}

// Round 9
// 59.138 us; speedup vs baseline: 1.5994x; 1.5994x over previous
//
#include <hip/hip_runtime.h>

#define HH 2160
#define WW 3840
#define K 31
#define RAD 15
#define TW 64
#define TH 16
#define IW 96             // staged cols: gx in [x0-16, x0+80)
#define IH 46             // TH + K - 1
#define NTHREADS 256
#define TMPW 100          // padded s_tmp row stride

#define GLDS(gp, lp) __builtin_amdgcn_global_load_lds(                         \
    (const __attribute__((address_space(1))) void*)(gp),                       \
    (__attribute__((address_space(3))) void*)(lp), 16, 0, 0)

__device__ __forceinline__ float fcomp(float4 v, int p) {
    switch (p) { case 0: return v.x; case 1: return v.y; case 2: return v.z; default: return v.w; }
}

__device__ __forceinline__ float uniformf(float x) {
    return __uint_as_float(__builtin_amdgcn_readfirstlane(__float_as_uint(x)));
}

__global__ __launch_bounds__(NTHREADS, 4) void blur_masked_kernel(
    const float* __restrict__ img, const float* __restrict__ mask,
    const float* __restrict__ kern, float* __restrict__ out)
{
    __shared__ float s_in[IH * IW];        // 17.25 KB
    __shared__ float s_tmp[TH * TMPW];     // 6.25 KB
    __shared__ float s_k1[K];

    const int b  = blockIdx.x;
    const int tx = b % 60;
    const int ty = b / 60;
    const int x0 = tx * TW;
    const int y0 = ty * TH;
    const int t  = threadIdx.x;

    // thread -> output pixels: row hr, 4 consecutive cols hc0..hc0+3
    const int hr  = t >> 4;         // 0..15
    const int hc0 = (t & 15) * 4;   // 0,4,...,60

    // ---- 1D kernel = row sums of 2D kernel (identical per channel) ----
    if (t < K) {
        float s = 0.f;
        const float* kr = kern + t * K;
        #pragma unroll
        for (int j = 0; j < K; ++j) s += kr[j];
        s_k1[t] = s;
    }

    // ---- mask + unconditional img prefetch (concurrent 16B loads; copy path
    //      uses them directly, blur path reuses them as blend iv) ----
    const size_t HW = (size_t)HH * WW;
    const size_t pix0 = (size_t)(y0 + hr) * WW + (x0 + hc0);
    float4 mv = *(const float4*)(mask + pix0);
    float4 i0 = *(const float4*)(img + pix0);
    float4 i1 = *(const float4*)(img + HW + pix0);
    float4 i2 = *(const float4*)(img + 2 * HW + pix0);

    int anyLocal = (mv.x != 0.f) | (mv.y != 0.f) | (mv.z != 0.f) | (mv.w != 0.f);
    int any = __syncthreads_or(anyLocal);   // also publishes s_k1

    if (!any) {
        // pure copy: out = img * 255, interleave in regs, 3 aligned float4
        float* ob = out + pix0 * 3;
        *(float4*)(ob)     = make_float4(i0.x * 255.f, i1.x * 255.f, i2.x * 255.f, i0.y * 255.f);
        *(float4*)(ob + 4) = make_float4(i1.y * 255.f, i2.y * 255.f, i0.z * 255.f, i1.z * 255.f);
        *(float4*)(ob + 8) = make_float4(i2.z * 255.f, i0.w * 255.f, i1.w * 255.f, i2.w * 255.f);
        return;
    }

    // taps -> SGPRs (wave-uniform)
    float k1r[K];
    #pragma unroll
    for (int j = 0; j < K; ++j) k1r[j] = uniformf(s_k1[j]);

    // interior tile: whole halo in-bounds
    const bool interior = (tx >= 1) && (tx <= 58) && (ty >= 1) && (ty <= 133);

    // staging mapping: 240 active threads = 10 rows x 24 float4-cols per round;
    // r,c computed ONCE, per-round address increment is a constant.
    const int sr  = t / 24;          // 0..9 active (t<240)
    const int sc  = t % 24;
    const bool sact = (t < 240);

    auto stage = [&](int ch) {
        const float* gp0 = img + (size_t)ch * HW
                         + (size_t)(y0 - RAD + sr) * WW + (x0 - 16 + 4 * sc);
        float* lp0 = s_in + sr * IW + 4 * sc;
        if (interior) {
            if (sact) {
                #pragma unroll
                for (int k2 = 0; k2 < 5; ++k2) {
                    if (sr + 10 * k2 < IH)
                        GLDS(gp0 + (size_t)(10 * k2) * WW, lp0 + 10 * k2 * IW);
                }
            }
        } else {
            #pragma unroll
            for (int k2 = 0; k2 < 5; ++k2) {
                int r = sr + 10 * k2;
                if (sact && r < IH) {
                    int gy = y0 - RAD + r, gx = x0 - 16 + 4 * sc;
                    float4 v = make_float4(0.f, 0.f, 0.f, 0.f);
                    if (gy >= 0 && gy < HH && gx >= 0 && gx < WW)
                        v = *(const float4*)(img + (size_t)ch * HW + (size_t)gy * WW + gx);
                    *(float4*)(s_in + r * IW + 4 * sc) = v;
                }
            }
        }
    };

    stage(0);

    float o[12];   // final interleaved pixels, built per channel

    // V-pass mapping: 192 active threads, each = (column, 8-row half)
    const int vc = t % 96;       // column 0..95
    const int vh = t / 96;       // 0,1 active; 2 = idle (t >= 192)

    #pragma unroll
    for (int ch = 0; ch < 3; ++ch) {
        __syncthreads();   // staging(ch) done; prev H-pass s_tmp reads done

        // ---- vertical pass: stream 38 rows once, 8 running accumulators ----
        if (vh < 2) {
            float acc[8] = {0.f, 0.f, 0.f, 0.f, 0.f, 0.f, 0.f, 0.f};
            const int ybase = vh * 8;
            #pragma unroll
            for (int s = 0; s < 38; ++s) {
                float v = s_in[(ybase + s) * IW + vc];
                #pragma unroll
                for (int j = 0; j < 8; ++j) {
                    if (s - j >= 0 && s - j <= 30) acc[j] += v * k1r[s - j];
                }
            }
            #pragma unroll
            for (int j = 0; j < 8; ++j)
                s_tmp[(ybase + j) * TMPW + vc] = acc[j];
        }

        __syncthreads();   // s_tmp ready; s_in free

        if (ch < 2) stage(ch + 1);   // HBM latency hides under H-pass

        // ---- horizontal pass: sliding window, 4 outputs/thread ----
        float a0 = 0.f, a1 = 0.f, a2 = 0.f, a3 = 0.f;
        const float* rowp = s_tmp + hr * TMPW + hc0;
        #pragma unroll
        for (int q = 0; q < 9; ++q) {
            float4 w = *(const float4*)(rowp + 4 * q);
            #pragma unroll
            for (int e = 0; e < 4; ++e) {
                const int idx = 4 * q + e;   // window col offset 0..35
                float v = fcomp(w, e);
                if (idx - 1 >= 0 && idx - 1 <= 30) a0 += v * k1r[idx - 1];
                if (idx - 2 >= 0 && idx - 2 <= 30) a1 += v * k1r[idx - 2];
                if (idx - 3 >= 0 && idx - 3 <= 30) a2 += v * k1r[idx - 3];
                if (idx - 4 >= 0 && idx - 4 <= 30) a3 += v * k1r[idx - 4];
            }
        }

        // ---- blend this channel into interleaved output registers ----
        float4 iv = (ch == 0) ? i0 : (ch == 1) ? i1 : i2;
        float bl[4] = {a0, a1, a2, a3};
        #pragma unroll
        for (int p = 0; p < 4; ++p) {
            float m = fcomp(mv, p);
            o[p * 3 + ch] = (fcomp(iv, p) * (1.f - m) + bl[p] * m) * 255.f;
        }
    }

    // ---- 3 aligned float4 stores (full-line coalesced) ----
    float* ob = out + pix0 * 3;
    *(float4*)(ob)     = make_float4(o[0], o[1], o[2],  o[3]);
    *(float4*)(ob + 4) = make_float4(o[4], o[5], o[6],  o[7]);
    *(float4*)(ob + 8) = make_float4(o[8], o[9], o[10], o[11]);
}

extern "C" void kernel_launch(void* const* d_in, const int* in_sizes, int n_in,
                              void* d_out, int out_size, void* d_ws, size_t ws_size,
                              hipStream_t stream) {
    const float* img  = (const float*)d_in[0];
    const float* mask = (const float*)d_in[1];
    const float* kern = (const float*)d_in[2];
    float* out = (float*)d_out;
    int nblocks = 60 * 135;  // 8100
    blur_masked_kernel<<<nblocks, NTHREADS, 0, stream>>>(img, mask, kern, out);
}